// Round 2
// baseline (341.394 us; speedup 1.0000x reference)
//
#include <hip/hip_runtime.h>

// SO3 tensor product, lmax=2: out[n,o,f] = sum_k cg[k]*x1[n,i1[k],f]*x2[n,i2[k],f]
// N_ATOMS=30000, S=9, N_FEAT=128, nnz ~ 83. Pure streaming: 276 MB read + 138 MB
// write => HBM floor ~66 us. R1 was 115 us, latency-bound at VGPR=64 (compiler
// batched the 18 upfront loads). R2: launch_bounds(256,4) to allow 128 VGPRs so
// all 18 loads stay in flight; per-output accumulate + immediate nontemporal
// store (acc live range = 1 float4); o-major dense CG for contiguous s_loads.

#define NS 9
#define NF 128
#define NF4 32  // NF/4

typedef float vf4 __attribute__((ext_vector_type(4)));

// l and m for each of the 9 real-SH slots (l=0; l=1 m=-1..1; l=2 m=-2..2)
constexpr int LQ[9] = {0, 1, 1, 1, 2, 2, 2, 2, 2};
constexpr int MQ[9] = {0, -1, 0, 1, -2, -1, 0, 1, 2};

// Structural nonzero test for real-SH CG (83 of 729 triples pass):
constexpr bool cg_compat(int A, int B, int O) {
  const int l1 = LQ[A], l2 = LQ[B], l3 = LQ[O];
  const int m1 = MQ[A], m2 = MQ[B], m3 = MQ[O];
  const int lo = (l1 > l2) ? (l1 - l2) : (l2 - l1);
  if (l3 < lo || l3 > l1 + l2) return false;
  if ((l1 + l2 + l3) & 1) return false;
  const int u = (m1 < 0) ? -m1 : m1;
  const int v = (m2 < 0) ? -m2 : m2;
  const int w = (m3 < 0) ? -m3 : m3;
  const int d = (u > v) ? (u - v) : (v - u);
  if (!(w == u + v || w == d)) return false;
  const bool mixed = (m1 < 0) != (m2 < 0);
  if (mixed != (m3 < 0)) return false;
  return true;
}

// o-major dense CG: C[o*81 + ia*9 + ib]
__global__ void build_dense_cg(const float* __restrict__ cg,
                               const int* __restrict__ i1,
                               const int* __restrict__ i2,
                               const int* __restrict__ io,
                               int nnz, float* __restrict__ C) {
  const int t = threadIdx.x;
  for (int i = t; i < NS * NS * NS; i += blockDim.x) C[i] = 0.0f;
  __syncthreads();
  for (int k = t; k < nnz; k += blockDim.x) {
    C[io[k] * (NS * NS) + i1[k] * NS + i2[k]] = cg[k];
  }
}

__global__ __launch_bounds__(256, 4) void so3_tp_kernel(
    const float4* __restrict__ x1, const float4* __restrict__ x2,
    const float* __restrict__ C, float4* __restrict__ out, int total) {
  const int tid = blockIdx.x * 256 + threadIdx.x;
  if (tid >= total) return;
  const int atom = tid >> 5;   // / NF4
  const int f4 = tid & 31;     // % NF4
  const int base = atom * (NS * NF4) + f4;

  const float4* ap = x1 + base;
  const float4* bp = x2 + base;

  // Issue all 18 loads up front — with the 128-VGPR budget they all stay in
  // flight (one vmcnt wait covers the lot).
  float4 a[NS], b[NS];
#pragma unroll
  for (int s = 0; s < NS; s++) a[s] = ap[s * NF4];
#pragma unroll
  for (int s = 0; s < NS; s++) b[s] = bp[s * NF4];

  float4* op = out + base;
#pragma unroll
  for (int o = 0; o < NS; o++) {
    float4 acc = make_float4(0.f, 0.f, 0.f, 0.f);
#pragma unroll
    for (int ia = 0; ia < NS; ia++) {
#pragma unroll
      for (int ib = 0; ib < NS; ib++) {
        if (cg_compat(ia, ib, o)) {
          const float c = C[o * (NS * NS) + ia * NS + ib];  // uniform -> s_load
          acc.x = fmaf(c, a[ia].x * b[ib].x, acc.x);
          acc.y = fmaf(c, a[ia].y * b[ib].y, acc.y);
          acc.z = fmaf(c, a[ia].z * b[ib].z, acc.z);
          acc.w = fmaf(c, a[ia].w * b[ib].w, acc.w);
        }
      }
    }
    // Write-only output: nontemporal store keeps L2/L3 free for input streams.
    __builtin_nontemporal_store(*(const vf4*)&acc, (vf4*)(op + o * NF4));
  }
}

extern "C" void kernel_launch(void* const* d_in, const int* in_sizes, int n_in,
                              void* d_out, int out_size, void* d_ws, size_t ws_size,
                              hipStream_t stream) {
  const float* x1 = (const float*)d_in[0];
  const float* x2 = (const float*)d_in[1];
  const float* cg = (const float*)d_in[2];
  const int* i1 = (const int*)d_in[3];
  const int* i2 = (const int*)d_in[4];
  const int* io = (const int*)d_in[5];

  const int nnz = in_sizes[2];
  const int natoms = in_sizes[0] / (NS * NF);
  float* C = (float*)d_ws;  // 729 floats scratch; rebuilt every call

  build_dense_cg<<<1, 256, 0, stream>>>(cg, i1, i2, io, nnz, C);

  const int total = natoms * NF4;
  const int blocks = (total + 255) / 256;
  so3_tp_kernel<<<blocks, 256, 0, stream>>>((const float4*)x1, (const float4*)x2, C,
                                            (float4*)d_out, total);
}

// Round 3
// 334.158 us; speedup vs baseline: 1.0217x; 1.0217x over previous
//
#include <hip/hip_runtime.h>

// SO3 tensor product, lmax=2: out[n,o,f] = sum_k cg[k]*x1[n,i1[k],f]*x2[n,i2[k],f]
// N_ATOMS=30000, S=9, N_FEAT=128, nnz ~ 83.
//
// Streaming kernel: 276 MB read + 138 MB write => HBM floor ~66 us @ 6.3 TB/s.
// R1/R2 sat at 115-133 us, latency-bound: compiler kept VGPR=64 and batched the
// 18 upfront loads (~2 KB/CU in flight vs ~9.2 KB needed by Little's law).
// R3: grid-stride loop, each thread handles ~4 (atom,f4) items with a register
// DOUBLE BUFFER — the 18 loads for item i+1 are issued before computing item i,
// so ~18 KB/wave stays in flight through the whole compute phase. Manual 2x
// unroll swaps buffer roles (no register copies). launch_bounds(256,2) gives a
// 256-VGPR budget for the ~200-VGPR double buffer. Plain stores (nt regressed).

#define NS 9
#define NF 128
#define NF4 32  // NF/4

// l and m for each of the 9 real-SH slots (l=0; l=1 m=-1..1; l=2 m=-2..2)
constexpr int LQ[9] = {0, 1, 1, 1, 2, 2, 2, 2, 2};
constexpr int MQ[9] = {0, -1, 0, 1, -2, -1, 0, 1, 2};

// Structural nonzero test for real-SH CG (83 of 729 triples pass):
constexpr bool cg_compat(int A, int B, int O) {
  const int l1 = LQ[A], l2 = LQ[B], l3 = LQ[O];
  const int m1 = MQ[A], m2 = MQ[B], m3 = MQ[O];
  const int lo = (l1 > l2) ? (l1 - l2) : (l2 - l1);
  if (l3 < lo || l3 > l1 + l2) return false;
  if ((l1 + l2 + l3) & 1) return false;
  const int u = (m1 < 0) ? -m1 : m1;
  const int v = (m2 < 0) ? -m2 : m2;
  const int w = (m3 < 0) ? -m3 : m3;
  const int d = (u > v) ? (u - v) : (v - u);
  if (!(w == u + v || w == d)) return false;
  const bool mixed = (m1 < 0) != (m2 < 0);
  if (mixed != (m3 < 0)) return false;
  return true;
}

// o-major dense CG: C[o*81 + ia*9 + ib]
__global__ void build_dense_cg(const float* __restrict__ cg,
                               const int* __restrict__ i1,
                               const int* __restrict__ i2,
                               const int* __restrict__ io,
                               int nnz, float* __restrict__ C) {
  const int t = threadIdx.x;
  for (int i = t; i < NS * NS * NS; i += blockDim.x) C[i] = 0.0f;
  __syncthreads();
  for (int k = t; k < nnz; k += blockDim.x) {
    C[io[k] * (NS * NS) + i1[k] * NS + i2[k]] = cg[k];
  }
}

__device__ __forceinline__ void load18(const float4* __restrict__ x1,
                                       const float4* __restrict__ x2,
                                       int idx, float4* a, float4* b) {
  const int atom = idx >> 5;   // / NF4
  const int f4 = idx & 31;     // % NF4
  const int base = atom * (NS * NF4) + f4;
#pragma unroll
  for (int s = 0; s < NS; s++) a[s] = x1[base + s * NF4];
#pragma unroll
  for (int s = 0; s < NS; s++) b[s] = x2[base + s * NF4];
}

__device__ __forceinline__ void compute_store(const float* __restrict__ C,
                                              const float4* a, const float4* b,
                                              float4* __restrict__ out, int idx) {
  const int atom = idx >> 5;
  const int f4 = idx & 31;
  const int base = atom * (NS * NF4) + f4;
#pragma unroll
  for (int o = 0; o < NS; o++) {
    float4 acc = make_float4(0.f, 0.f, 0.f, 0.f);
#pragma unroll
    for (int ia = 0; ia < NS; ia++) {
#pragma unroll
      for (int ib = 0; ib < NS; ib++) {
        if (cg_compat(ia, ib, o)) {
          const float c = C[o * (NS * NS) + ia * NS + ib];  // uniform -> s_load
          acc.x = fmaf(c, a[ia].x * b[ib].x, acc.x);
          acc.y = fmaf(c, a[ia].y * b[ib].y, acc.y);
          acc.z = fmaf(c, a[ia].z * b[ib].z, acc.z);
          acc.w = fmaf(c, a[ia].w * b[ib].w, acc.w);
        }
      }
    }
    out[base + o * NF4] = acc;
  }
}

__global__ __launch_bounds__(256, 2) void so3_tp_kernel(
    const float4* __restrict__ x1, const float4* __restrict__ x2,
    const float* __restrict__ C, float4* __restrict__ out, int total) {
  int idx = blockIdx.x * 256 + threadIdx.x;
  const int stride = gridDim.x * 256;

  float4 A1[NS], B1[NS], A2[NS], B2[NS];

  if (idx >= total) return;
  load18(x1, x2, idx, A1, B1);  // prime the pipeline

  while (true) {
    // half 1: prefetch idx+stride into buf2, compute from buf1
    int n1 = idx + stride;
    if (n1 < total) load18(x1, x2, n1, A2, B2);
    compute_store(C, A1, B1, out, idx);
    if (n1 >= total) return;
    idx = n1;

    // half 2: prefetch idx+stride into buf1, compute from buf2
    int n2 = idx + stride;
    if (n2 < total) load18(x1, x2, n2, A1, B1);
    compute_store(C, A2, B2, out, idx);
    if (n2 >= total) return;
    idx = n2;
  }
}

extern "C" void kernel_launch(void* const* d_in, const int* in_sizes, int n_in,
                              void* d_out, int out_size, void* d_ws, size_t ws_size,
                              hipStream_t stream) {
  const float* x1 = (const float*)d_in[0];
  const float* x2 = (const float*)d_in[1];
  const float* cg = (const float*)d_in[2];
  const int* i1 = (const int*)d_in[3];
  const int* i2 = (const int*)d_in[4];
  const int* io = (const int*)d_in[5];

  const int nnz = in_sizes[2];
  const int natoms = in_sizes[0] / (NS * NF);
  float* C = (float*)d_ws;  // 729 floats scratch; rebuilt every call

  build_dense_cg<<<1, 256, 0, stream>>>(cg, i1, i2, io, nnz, C);

  const int total = natoms * NF4;                  // 960000 work items
  int blocks = (total + 255) / 256;
  if (blocks > 960) blocks = 960;                  // ~4 items/thread -> 75% of
                                                   // loads are prefetched
  so3_tp_kernel<<<blocks, 256, 0, stream>>>((const float4*)x1, (const float4*)x2, C,
                                            (float4*)d_out, total);
}